// Round 11
// baseline (33.765 us; speedup 1.0000x reference)
//
#include <hip/hip_runtime.h>

#ifndef NUM_CLASSES
#define NUM_CLASSES 10
#endif

// x: (B=64, TS=128, C=1, H=64, W=64) fp32 -> K = 4096
// Derivation: with F_THRESH=0, h_t == frame_{t-1} exactly, so
//   out[b,c] = ( sum_k Wfc[c,k] * S[b,k] + (TS-1)*bfc[c] ) / TS,
//   S[b,k]   = sum_{t=1..TS-1} sign3(x[b,t,k] - x[b,t-1,k])
// R11 = R5 (best: 30.15us; two kernels -- R7/R8/R10 proved every
// single-kernel epilogue variant costs more than the graph edge) with ONE
// change: Wfc is preloaded into registers BEFORE the streaming t-loop
// (80 VGPR/thread; ~120 total keeps 16 waves/CU). In R5 every block read
// the full 160KB Wfc AFTER its stream -> 80MB synchronized L2 burst
// (~2.3us serial tail). Preloading overlaps it with the HBM stream and
// makes the epilogue pure register FMAs. asm-use pins stop the compiler
// from sinking the loads back past the loop.
constexpr int B_        = 64;
constexpr int TS_       = 128;
constexpr int K_        = 4096;
constexpr int THREADS_  = 512;
constexpr int TCHUNKS_  = 8;
constexpr int TSTEP_    = 16;                      // diffs per chunk (last: 15)
constexpr int NPART_    = TCHUNKS_;                // 8 partials per (b,c)
constexpr int NWAVES_   = THREADS_ / 64;           // 8

// Kernel 1: per-(b,tc) block: preload Wfc regs, stream full frames,
// accumulate sign3 per k, register-FMA FC -> 10 partial logits.
// Grid: (B_, TCHUNKS_) = 512 blocks, block: 512.
__global__ __launch_bounds__(THREADS_) void sign_fc_kernel(
    const float* __restrict__ x, const float* __restrict__ Wfc,
    float* __restrict__ P)
{
    const int b   = blockIdx.x;
    const int tc  = blockIdx.y;
    const int tid = threadIdx.x;

    const int t_begin = tc * TSTEP_;
    const int t_end   = (tc == TCHUNKS_ - 1) ? (TS_ - 1) : (t_begin + TSTEP_);

    // Thread owns 8 k's: tid*4 + {0..3} and 2048 + tid*4 + {0..3}.
    const int kbase = tid * 4;

    // ---- Preload Wfc fragments (L2-resident after first touch) ----
    float4 W0[NUM_CLASSES], W1[NUM_CLASSES];
#pragma unroll
    for (int c = 0; c < NUM_CLASSES; ++c) {
        const float* wr = Wfc + (size_t)c * K_ + kbase;
        W0[c] = *reinterpret_cast<const float4*>(wr);
        W1[c] = *reinterpret_cast<const float4*>(wr + 2048);
    }
    // Pin: force the loads to complete here (before the stream loop) so the
    // scheduler can't sink them into a post-loop serial L2 burst.
#pragma unroll
    for (int c = 0; c < NUM_CLASSES; ++c) {
        asm volatile("" :: "v"(W0[c].x), "v"(W0[c].y), "v"(W0[c].z), "v"(W0[c].w));
        asm volatile("" :: "v"(W1[c].x), "v"(W1[c].y), "v"(W1[c].z), "v"(W1[c].w));
    }

    // ---- Stream 17 contiguous 16KB frames, accumulate sign sums ----
    const float* xp = x + ((size_t)b * TS_ + t_begin) * K_ + kbase;
    float4 prev0 = *reinterpret_cast<const float4*>(xp);
    float4 prev1 = *reinterpret_cast<const float4*>(xp + 2048);

    int s0 = 0, s1 = 0, s2 = 0, s3 = 0, s4 = 0, s5 = 0, s6 = 0, s7 = 0;

#pragma unroll 4
    for (int t = t_begin + 1; t <= t_end; ++t) {
        xp += K_;
        const float4 cur0 = *reinterpret_cast<const float4*>(xp);
        const float4 cur1 = *reinterpret_cast<const float4*>(xp + 2048);
        float d;
        d = cur0.x - prev0.x; s0 += (d > 0.0f) - (d < 0.0f);
        d = cur0.y - prev0.y; s1 += (d > 0.0f) - (d < 0.0f);
        d = cur0.z - prev0.z; s2 += (d > 0.0f) - (d < 0.0f);
        d = cur0.w - prev0.w; s3 += (d > 0.0f) - (d < 0.0f);
        d = cur1.x - prev1.x; s4 += (d > 0.0f) - (d < 0.0f);
        d = cur1.y - prev1.y; s5 += (d > 0.0f) - (d < 0.0f);
        d = cur1.z - prev1.z; s6 += (d > 0.0f) - (d < 0.0f);
        d = cur1.w - prev1.w; s7 += (d > 0.0f) - (d < 0.0f);
        prev0 = cur0;
        prev1 = cur1;
    }

    const float f0 = (float)s0, f1 = (float)s1, f2 = (float)s2, f3 = (float)s3;
    const float f4 = (float)s4, f5 = (float)s5, f6 = (float)s6, f7 = (float)s7;

    // ---- FC epilogue: pure register FMAs ----
    float acc[NUM_CLASSES];
#pragma unroll
    for (int c = 0; c < NUM_CLASSES; ++c) {
        acc[c] = f0 * W0[c].x + f1 * W0[c].y + f2 * W0[c].z + f3 * W0[c].w
               + f4 * W1[c].x + f5 * W1[c].y + f6 * W1[c].z + f7 * W1[c].w;
    }

    // Wave-shuffle reduce (fixed order, deterministic), then 8-wave combine.
#pragma unroll
    for (int off = 32; off > 0; off >>= 1) {
#pragma unroll
        for (int c = 0; c < NUM_CLASSES; ++c)
            acc[c] += __shfl_down(acc[c], off, 64);
    }

    __shared__ float red[NUM_CLASSES][NWAVES_];
    const int wave = tid >> 6;
    const int lane = tid & 63;
    if (lane == 0) {
#pragma unroll
        for (int c = 0; c < NUM_CLASSES; ++c) red[c][wave] = acc[c];
    }
    __syncthreads();

    if (tid < NUM_CLASSES) {
        float v = 0.0f;
#pragma unroll
        for (int w = 0; w < NWAVES_; ++w) v += red[tid][w];
        P[((size_t)b * NUM_CLASSES + tid) * NPART_ + tc] = v;
    }
}

// Kernel 2: out[b][c] = (sum_{i<8} P[b][c][i] + (TS-1)*bfc[c]) / TS
// Grid: B_, block: 64. Fixed-order -> bit-deterministic.
__global__ __launch_bounds__(64) void fc_finish_kernel(
    const float* __restrict__ P, const float* __restrict__ bfc,
    float* __restrict__ out)
{
    const int b = blockIdx.x;
    const int c = threadIdx.x;
    if (c >= NUM_CLASSES) return;

    const float* p = P + ((size_t)b * NUM_CLASSES + c) * NPART_;
    float s = 0.0f;
#pragma unroll
    for (int i = 0; i < NPART_; ++i) s += p[i];

    out[b * NUM_CLASSES + c] = (s + (float)(TS_ - 1) * bfc[c]) * (1.0f / (float)TS_);
}

extern "C" void kernel_launch(void* const* d_in, const int* in_sizes, int n_in,
                              void* d_out, int out_size, void* d_ws, size_t ws_size,
                              hipStream_t stream)
{
    const float* x   = (const float*)d_in[0];
    const float* Wfc = (const float*)d_in[1];
    const float* bfc = (const float*)d_in[2];
    float* out = (float*)d_out;
    float* P = (float*)d_ws;   // needs B_*NUM_CLASSES*NPART_*4 = 20 KiB

    dim3 grid1(B_, TCHUNKS_);
    sign_fc_kernel<<<grid1, THREADS_, 0, stream>>>(x, Wfc, P);

    fc_finish_kernel<<<B_, 64, 0, stream>>>(P, bfc, out);
}

// Round 12
// 29.822 us; speedup vs baseline: 1.1322x; 1.1322x over previous
//
#include <hip/hip_runtime.h>

#ifndef NUM_CLASSES
#define NUM_CLASSES 10
#endif

// x: (B=64, TS=128, C=1, H=64, W=64) fp32 -> K = 4096
// Derivation: with F_THRESH=0, h_t == frame_{t-1} exactly, so
//   out[b,c] = ( sum_k Wfc[c,k] * S[b,k] + (TS-1)*bfc[c] ) / TS,
//   S[b,k]   = sum_{t=1..TS-1} sign3(x[b,t,k] - x[b,t-1,k])
// R12 = R5 verbatim (best measured: 30.15us). Block (b,tc) streams 17 full
// 16KB frames = 272KB fully contiguous; FC fused per-thread (Wfc loaded
// post-stream, L2-resident); wave-shuffle + LDS reduce; tiny finish kernel.
// Variants that REGRESSED vs this: nontemporal loads (R7), single-kernel
// fusion w/ tickets (R8: +14us, device-scope atomic+fence cost), 1024-thr
// blocks (R9: less per-thread ILP), distributed atomicAdd epilogue (R10),
// register Wfc preload (R11: VGPR>128 occupancy cliff).
constexpr int B_        = 64;
constexpr int TS_       = 128;
constexpr int K_        = 4096;
constexpr int THREADS_  = 512;
constexpr int TCHUNKS_  = 8;
constexpr int TSTEP_    = 16;                      // diffs per chunk (last: 15)
constexpr int NPART_    = TCHUNKS_;                // 8 partials per (b,c)
constexpr int NWAVES_   = THREADS_ / 64;           // 8

// Kernel 1: per-(b,tc) block: stream full frames, accumulate sign3 per k,
// fused FC -> 10 partial logits.
// Grid: (B_, TCHUNKS_) = 512 blocks, block: 512.
__global__ __launch_bounds__(THREADS_) void sign_fc_kernel(
    const float* __restrict__ x, const float* __restrict__ Wfc,
    float* __restrict__ P)
{
    const int b   = blockIdx.x;
    const int tc  = blockIdx.y;
    const int tid = threadIdx.x;

    const int t_begin = tc * TSTEP_;
    const int t_end   = (tc == TCHUNKS_ - 1) ? (TS_ - 1) : (t_begin + TSTEP_);

    // Thread owns 8 k's: tid*4 + {0..3} and 2048 + tid*4 + {0..3}.
    const int kbase = tid * 4;

    const float* xp = x + ((size_t)b * TS_ + t_begin) * K_ + kbase;
    float4 prev0 = *reinterpret_cast<const float4*>(xp);
    float4 prev1 = *reinterpret_cast<const float4*>(xp + 2048);

    int s0 = 0, s1 = 0, s2 = 0, s3 = 0, s4 = 0, s5 = 0, s6 = 0, s7 = 0;

#pragma unroll 4
    for (int t = t_begin + 1; t <= t_end; ++t) {
        xp += K_;
        const float4 cur0 = *reinterpret_cast<const float4*>(xp);
        const float4 cur1 = *reinterpret_cast<const float4*>(xp + 2048);
        float d;
        d = cur0.x - prev0.x; s0 += (d > 0.0f) - (d < 0.0f);
        d = cur0.y - prev0.y; s1 += (d > 0.0f) - (d < 0.0f);
        d = cur0.z - prev0.z; s2 += (d > 0.0f) - (d < 0.0f);
        d = cur0.w - prev0.w; s3 += (d > 0.0f) - (d < 0.0f);
        d = cur1.x - prev1.x; s4 += (d > 0.0f) - (d < 0.0f);
        d = cur1.y - prev1.y; s5 += (d > 0.0f) - (d < 0.0f);
        d = cur1.z - prev1.z; s6 += (d > 0.0f) - (d < 0.0f);
        d = cur1.w - prev1.w; s7 += (d > 0.0f) - (d < 0.0f);
        prev0 = cur0;
        prev1 = cur1;
    }

    const float f0 = (float)s0, f1 = (float)s1, f2 = (float)s2, f3 = (float)s3;
    const float f4 = (float)s4, f5 = (float)s5, f6 = (float)s6, f7 = (float)s7;

    // Fused FC: per-thread dot over its 8 k's. Wfc (160KB) is L2/L3-resident.
    float acc[NUM_CLASSES];
#pragma unroll
    for (int c = 0; c < NUM_CLASSES; ++c) {
        const float* wr = Wfc + (size_t)c * K_ + kbase;
        const float4 w0 = *reinterpret_cast<const float4*>(wr);
        const float4 w1 = *reinterpret_cast<const float4*>(wr + 2048);
        acc[c] = f0 * w0.x + f1 * w0.y + f2 * w0.z + f3 * w0.w
               + f4 * w1.x + f5 * w1.y + f6 * w1.z + f7 * w1.w;
    }

    // Wave-shuffle reduce (fixed order, deterministic), then 8-wave combine.
#pragma unroll
    for (int off = 32; off > 0; off >>= 1) {
#pragma unroll
        for (int c = 0; c < NUM_CLASSES; ++c)
            acc[c] += __shfl_down(acc[c], off, 64);
    }

    __shared__ float red[NUM_CLASSES][NWAVES_];
    const int wave = tid >> 6;
    const int lane = tid & 63;
    if (lane == 0) {
#pragma unroll
        for (int c = 0; c < NUM_CLASSES; ++c) red[c][wave] = acc[c];
    }
    __syncthreads();

    if (tid < NUM_CLASSES) {
        float v = 0.0f;
#pragma unroll
        for (int w = 0; w < NWAVES_; ++w) v += red[tid][w];
        P[((size_t)b * NUM_CLASSES + tid) * NPART_ + tc] = v;
    }
}

// Kernel 2: out[b][c] = (sum_{i<8} P[b][c][i] + (TS-1)*bfc[c]) / TS
// Grid: B_, block: 64. Fixed-order -> bit-deterministic.
__global__ __launch_bounds__(64) void fc_finish_kernel(
    const float* __restrict__ P, const float* __restrict__ bfc,
    float* __restrict__ out)
{
    const int b = blockIdx.x;
    const int c = threadIdx.x;
    if (c >= NUM_CLASSES) return;

    const float* p = P + ((size_t)b * NUM_CLASSES + c) * NPART_;
    float s = 0.0f;
#pragma unroll
    for (int i = 0; i < NPART_; ++i) s += p[i];

    out[b * NUM_CLASSES + c] = (s + (float)(TS_ - 1) * bfc[c]) * (1.0f / (float)TS_);
}

extern "C" void kernel_launch(void* const* d_in, const int* in_sizes, int n_in,
                              void* d_out, int out_size, void* d_ws, size_t ws_size,
                              hipStream_t stream)
{
    const float* x   = (const float*)d_in[0];
    const float* Wfc = (const float*)d_in[1];
    const float* bfc = (const float*)d_in[2];
    float* out = (float*)d_out;
    float* P = (float*)d_ws;   // needs B_*NUM_CLASSES*NPART_*4 = 20 KiB

    dim3 grid1(B_, TCHUNKS_);
    sign_fc_kernel<<<grid1, THREADS_, 0, stream>>>(x, Wfc, P);

    fc_finish_kernel<<<B_, 64, 0, stream>>>(P, bfc, out);
}